// Round 3
// baseline (193.938 us; speedup 1.0000x reference)
//
#include <hip/hip_runtime.h>
#include <hip/hip_cooperative_groups.h>
#include <hip/hip_bf16.h>
#include <hip/hip_fp16.h>

typedef _Float16 half8_t  __attribute__((ext_vector_type(8)));
typedef short    short8_t __attribute__((ext_vector_type(8)));
typedef short    short4_t __attribute__((ext_vector_type(4)));
typedef float    f32x4    __attribute__((ext_vector_type(4)));

#define LOG2E 1.44269504088896f

__device__ __forceinline__ unsigned pack_bf16_2(float lo, float hi) {
  float2 f2; f2.x = lo; f2.y = hi;
  __hip_bfloat162 h2 = __float22bfloat162_rn(f2);
  return *reinterpret_cast<unsigned*>(&h2);
}

// ---------------------------------------------------------------------------
// v16: FUSED prep+attn, cooperative launch (256 blocks x 512 thr, 1 block/CU).
// Phase 1 (prep): block p computes projections for positions [p*64, p*64+64):
//   C = x[64x64] @ W[64x80] via 16x16x32 f16 MFMA; W^T staged in LDS.
//   8 waves: wave (wr,half) -> row-tile wr=wv&3, channel-half (nt 0-2 | 3-4).
//   Outputs (attn's exact layouts): f key-permuted slots, g (x log2e), vT bf16.
// __threadfence + grid.sync() -> cross-XCD visibility, intermediates L2-warm.
// Phase 2 (attn): identical to v15 (64 queries/block, wave w = keys
//   [w*512,+512), phase-staggered chunks, exp2-as-PV-B-frags, ones-MFMA
//   denominator, ping-pong prefetch, LDS cross-wave combine).
// LDS time-shared: prep WtT+ball (11.8 KB) then red[7][64][17] (30.5 KB).
// ---------------------------------------------------------------------------
__device__ __forceinline__ void compute_chunk(
    const half8_t& f0, const half8_t& f1,
    const short8_t& v0, const short8_t& v1,
    const short8_t& v2, const short8_t& v3,
    const half8_t (&gfrag)[4], const short8_t& ones8,
    f32x4 (&acc)[4][4], f32x4 (&acc4)[4])
{
  const f32x4 zc = {0.f, 0.f, 0.f, 0.f};
#pragma unroll
  for (int tt = 0; tt < 4; tt++) {
    f32x4 s0 = __builtin_amdgcn_mfma_f32_16x16x32_f16(f0, gfrag[tt], zc, 0, 0, 0);
    f32x4 s1 = __builtin_amdgcn_mfma_f32_16x16x32_f16(f1, gfrag[tt], zc, 0, 0, 0);
    float p00 = __builtin_amdgcn_exp2f(s0[0]), p01 = __builtin_amdgcn_exp2f(s0[1]);
    float p02 = __builtin_amdgcn_exp2f(s0[2]), p03 = __builtin_amdgcn_exp2f(s0[3]);
    float p10 = __builtin_amdgcn_exp2f(s1[0]), p11 = __builtin_amdgcn_exp2f(s1[1]);
    float p12 = __builtin_amdgcn_exp2f(s1[2]), p13 = __builtin_amdgcn_exp2f(s1[3]);
    union { unsigned u[4]; short8_t v; } pu;
    pu.u[0] = pack_bf16_2(p00, p01);
    pu.u[1] = pack_bf16_2(p02, p03);
    pu.u[2] = pack_bf16_2(p10, p11);
    pu.u[3] = pack_bf16_2(p12, p13);
    short8_t pfrag = pu.v;
    acc[tt][0] = __builtin_amdgcn_mfma_f32_16x16x32_bf16(v0, pfrag, acc[tt][0], 0, 0, 0);
    acc[tt][1] = __builtin_amdgcn_mfma_f32_16x16x32_bf16(v1, pfrag, acc[tt][1], 0, 0, 0);
    acc[tt][2] = __builtin_amdgcn_mfma_f32_16x16x32_bf16(v2, pfrag, acc[tt][2], 0, 0, 0);
    acc[tt][3] = __builtin_amdgcn_mfma_f32_16x16x32_bf16(v3, pfrag, acc[tt][3], 0, 0, 0);
    acc4[tt]   = __builtin_amdgcn_mfma_f32_16x16x32_bf16(ones8, pfrag, acc4[tt], 0, 0, 0);
  }
}

__global__ __launch_bounds__(512, 2) void fused_kernel(
    const float* __restrict__ x,
    const float* __restrict__ Wf, const float* __restrict__ bf,
    const float* __restrict__ Wg, const float* __restrict__ bg,
    const float* __restrict__ Wh, const float* __restrict__ bh,
    _Float16* __restrict__ fh, _Float16* __restrict__ gh,
    unsigned short* __restrict__ vT,
    float* __restrict__ out)
{
  namespace cg = cooperative_groups;
  __shared__ __align__(16) char smraw[7 * 64 * 17 * 4];   // 30464 B, time-shared

  const int t    = threadIdx.x;
  const int lane = t & 63;
  const int wv   = t >> 6;
  const int quad = lane >> 4;
  const int l15  = lane & 15;

  // ================= Phase 1: prep =================
  {
    _Float16* WtT = (_Float16*)smraw;            // [80][72]
    float*    ball = (float*)(smraw + 80 * 72 * 2);

    {
      int i = t;  // 512 threads cover Wf/Wg in one pass
      int c = i >> 3, d = i & 7;
      WtT[d * 72 + c]       = (_Float16)Wf[i];
      WtT[(8 + d) * 72 + c] = (_Float16)(Wg[i] * LOG2E);
    }
    for (int i = t; i < 4096; i += 512) {
      int c = i >> 6, ch = i & 63;
      WtT[(16 + ch) * 72 + c] = (_Float16)Wh[i];
    }
    if (t < 80) ball[t] = (t < 8) ? bf[t] : (t < 16) ? bg[t - 8] * LOG2E : bh[t - 16];
    __syncthreads();

    const int wr   = wv & 3;       // row tile
    const int half = wv >> 2;      // 0: nt 0..2, 1: nt 3..4
    const int p0  = blockIdx.x * 64;
    const int row = p0 + wr * 16 + l15;

    const float* xr = x + (size_t)row * 64 + quad * 8;
    float4 xa = *(const float4*)(xr);
    float4 xb = *(const float4*)(xr + 4);
    float4 xc = *(const float4*)(xr + 32);
    float4 xd = *(const float4*)(xr + 36);
    half8_t a0, a1;
    a0[0]=(_Float16)xa.x; a0[1]=(_Float16)xa.y; a0[2]=(_Float16)xa.z; a0[3]=(_Float16)xa.w;
    a0[4]=(_Float16)xb.x; a0[5]=(_Float16)xb.y; a0[6]=(_Float16)xb.z; a0[7]=(_Float16)xb.w;
    a1[0]=(_Float16)xc.x; a1[1]=(_Float16)xc.y; a1[2]=(_Float16)xc.z; a1[3]=(_Float16)xc.w;
    a1[4]=(_Float16)xd.x; a1[5]=(_Float16)xd.y; a1[6]=(_Float16)xd.z; a1[7]=(_Float16)xd.w;

    const f32x4 zc = {0.f, 0.f, 0.f, 0.f};
    const int b     = p0 >> 12;
    const int nbase = (p0 & 4095) + wr * 16 + quad * 4;
    const int kblock = nbase >> 5;
    const int r0     = nbase & 31;
    const int q8 = r0 >> 3, j8 = r0 & 7;
    const int slot0 = (j8 < 4) ? (q8 * 4 + j8) : (16 + q8 * 4 + (j8 - 4));
    const size_t fbase_out = ((size_t)b * 4096 + (kblock << 5) + slot0) * 8;
    const size_t gbase_out = ((size_t)p0 + wr * 16 + quad * 4) * 8;
    const size_t vbase_out = (((size_t)b * 128 + kblock) << 11) + r0;

    if (half == 0) {
      // nt = 0: f (ch 0-7) / g (ch 8-15)
      {
        const _Float16* wt = &WtT[l15 * 72 + quad * 8];
        half8_t b0 = *(const half8_t*)(wt);
        half8_t b1 = *(const half8_t*)(wt + 32);
        f32x4 d = __builtin_amdgcn_mfma_f32_16x16x32_f16(a0, b0, zc, 0, 0, 0);
        d = __builtin_amdgcn_mfma_f32_16x16x32_f16(a1, b1, d, 0, 0, 0);
        const float bias = ball[l15];
        if (l15 < 8) {
#pragma unroll
          for (int reg = 0; reg < 4; reg++)
            fh[fbase_out + (size_t)reg * 8 + l15] = (_Float16)(d[reg] + bias);
        } else {
#pragma unroll
          for (int reg = 0; reg < 4; reg++)
            gh[gbase_out + (size_t)reg * 8 + (l15 - 8)] = (_Float16)(d[reg] + bias);
        }
      }
#pragma unroll
      for (int nt = 1; nt < 3; nt++) {
        const int ch0 = nt * 16 + l15;
        const _Float16* wt = &WtT[ch0 * 72 + quad * 8];
        half8_t b0 = *(const half8_t*)(wt);
        half8_t b1 = *(const half8_t*)(wt + 32);
        f32x4 d = __builtin_amdgcn_mfma_f32_16x16x32_f16(a0, b0, zc, 0, 0, 0);
        d = __builtin_amdgcn_mfma_f32_16x16x32_f16(a1, b1, d, 0, 0, 0);
        const float bias = ball[ch0];
        const int vch = ch0 - 16;
        union { unsigned u[2]; short4_t s; } pk;
        pk.u[0] = pack_bf16_2(d[0] + bias, d[1] + bias);
        pk.u[1] = pack_bf16_2(d[2] + bias, d[3] + bias);
        *(short4_t*)(vT + vbase_out + (size_t)vch * 32) = pk.s;
      }
    } else {
#pragma unroll
      for (int nt = 3; nt < 5; nt++) {
        const int ch0 = nt * 16 + l15;
        const _Float16* wt = &WtT[ch0 * 72 + quad * 8];
        half8_t b0 = *(const half8_t*)(wt);
        half8_t b1 = *(const half8_t*)(wt + 32);
        f32x4 d = __builtin_amdgcn_mfma_f32_16x16x32_f16(a0, b0, zc, 0, 0, 0);
        d = __builtin_amdgcn_mfma_f32_16x16x32_f16(a1, b1, d, 0, 0, 0);
        const float bias = ball[ch0];
        const int vch = ch0 - 16;
        union { unsigned u[2]; short4_t s; } pk;
        pk.u[0] = pack_bf16_2(d[0] + bias, d[1] + bias);
        pk.u[1] = pack_bf16_2(d[2] + bias, d[3] + bias);
        *(short4_t*)(vT + vbase_out + (size_t)vch * 32) = pk.s;
      }
    }
  }

  __threadfence();            // device-scope: flush fh/gh/vT for cross-XCD readers
  cg::this_grid().sync();

  // ================= Phase 2: attn (v15) =================
  const int N    = 4096;
  const int w    = wv;                     // 0..7 = key range
  float* red = (float*)smraw;              // [7][64][17]

  const int xcd = blockIdx.x & 7;
  const int b   = xcd >> 1;
  const int qg  = ((blockIdx.x >> 3) << 1) + (xcd & 1);  // 0..63
  const int q0  = qg * 64;
  const int kbase = w * 512;
  const int phase = (qg >> 1) & 15;        // stagger: de-correlate L2 streams

  const _Float16* fbase = fh + (size_t)b * N * 8;
  const _Float16* gbase = gh + (size_t)b * N * 8;
  const short*    vbat  = (const short*)vT + (size_t)b * 262144 + (l15 << 5) + (quad << 3);

  half8_t gfrag[4] = {{}, {}, {}, {}};
  if (quad == 0) {
#pragma unroll
    for (int tt = 0; tt < 4; tt++)
      gfrag[tt] = *(const half8_t*)(gbase + (size_t)(q0 + tt * 16 + l15) * 8);
  }

  const f32x4 zc = {0.f, 0.f, 0.f, 0.f};
  f32x4 acc[4][4];
  f32x4 acc4[4];
#pragma unroll
  for (int tt = 0; tt < 4; tt++) {
    acc4[tt] = zc;
#pragma unroll
    for (int ct = 0; ct < 4; ct++) acc[tt][ct] = zc;
  }

  short8_t ones8;
#pragma unroll
  for (int i = 0; i < 8; i++) ones8[i] = (short)0x3F80;

  // ping-pong load buffers
  half8_t  fa0 = {}, fa1 = {}, fb0 = {}, fb1 = {};
  short8_t va0, va1, va2, va3, vb0, vb1, vb2, vb3;

  {
    const int k0 = kbase + (((0 + phase) & 15) << 5);
    if (quad == 0) {
      fa0 = *(const half8_t*)(fbase + (size_t)(k0 + l15) * 8);
      fa1 = *(const half8_t*)(fbase + (size_t)(k0 + 16 + l15) * 8);
    }
    const short* vk = vbat + ((size_t)(k0 >> 5) << 11);
    va0 = *(const short8_t*)(vk);
    va1 = *(const short8_t*)(vk + 512);
    va2 = *(const short8_t*)(vk + 1024);
    va3 = *(const short8_t*)(vk + 1536);
  }

#pragma unroll 1
  for (int cc = 0; cc < 16; cc += 2) {
    {
      const int k1 = kbase + (((cc + 1 + phase) & 15) << 5);
      if (quad == 0) {
        fb0 = *(const half8_t*)(fbase + (size_t)(k1 + l15) * 8);
        fb1 = *(const half8_t*)(fbase + (size_t)(k1 + 16 + l15) * 8);
      }
      const short* vk = vbat + ((size_t)(k1 >> 5) << 11);
      vb0 = *(const short8_t*)(vk);
      vb1 = *(const short8_t*)(vk + 512);
      vb2 = *(const short8_t*)(vk + 1024);
      vb3 = *(const short8_t*)(vk + 1536);
    }
    compute_chunk(fa0, fa1, va0, va1, va2, va3, gfrag, ones8, acc, acc4);
    if (cc + 2 < 16) {
      const int k2 = kbase + (((cc + 2 + phase) & 15) << 5);
      if (quad == 0) {
        fa0 = *(const half8_t*)(fbase + (size_t)(k2 + l15) * 8);
        fa1 = *(const half8_t*)(fbase + (size_t)(k2 + 16 + l15) * 8);
      }
      const short* vk = vbat + ((size_t)(k2 >> 5) << 11);
      va0 = *(const short8_t*)(vk);
      va1 = *(const short8_t*)(vk + 512);
      va2 = *(const short8_t*)(vk + 1024);
      va3 = *(const short8_t*)(vk + 1536);
    }
    compute_chunk(fb0, fb1, vb0, vb1, vb2, vb3, gfrag, ones8, acc, acc4);
  }

  // ---- cross-wave combine: 4 sequential phases, 7 partials each ----
#pragma unroll 1
  for (int tt = 0; tt < 4; tt++) {
    if (w > 0) {
      float* p = &red[((w - 1) * 64 + lane) * 17];
#pragma unroll
      for (int ct = 0; ct < 4; ct++)
#pragma unroll
        for (int reg = 0; reg < 4; reg++) p[ct * 4 + reg] = acc[tt][ct][reg];
      p[16] = acc4[tt][0];
    }
    __syncthreads();
    if (w == 0) {
      f32x4 a0 = acc[tt][0], a1 = acc[tt][1], a2 = acc[tt][2], a3 = acc[tt][3];
      float lv = acc4[tt][0];
#pragma unroll
      for (int ww = 0; ww < 7; ww++) {
        const float* p = &red[(ww * 64 + lane) * 17];
#pragma unroll
        for (int reg = 0; reg < 4; reg++) {
          a0[reg] += p[0 + reg];
          a1[reg] += p[4 + reg];
          a2[reg] += p[8 + reg];
          a3[reg] += p[12 + reg];
        }
        lv += p[16];
      }
      const float inv = 1.0f / lv;
      float* ob = out + ((size_t)b * N + q0 + tt * 16 + l15) * 64 + (quad << 2);
      *(f32x4*)(ob)      = a0 * inv;
      *(f32x4*)(ob + 16) = a1 * inv;
      *(f32x4*)(ob + 32) = a2 * inv;
      *(f32x4*)(ob + 48) = a3 * inv;
    }
    __syncthreads();
  }
}

// ---------------------------------------------------------------------------
extern "C" void kernel_launch(void* const* d_in, const int* in_sizes, int n_in,
                              void* d_out, int out_size, void* d_ws, size_t ws_size,
                              hipStream_t stream) {
  const float* x  = (const float*)d_in[0];
  const float* Wf = (const float*)d_in[1];
  const float* bf = (const float*)d_in[2];
  const float* Wg = (const float*)d_in[3];
  const float* bg = (const float*)d_in[4];
  const float* Wh = (const float*)d_in[5];
  const float* bh = (const float*)d_in[6];
  float* out = (float*)d_out;

  char* ws = (char*)d_ws;
  _Float16* fh = (_Float16*)ws;                        // 256 KB
  _Float16* gh = (_Float16*)(ws + 262144);             // 256 KB
  unsigned short* vT = (unsigned short*)(ws + 524288); // 2 MB

  void* args[] = {(void*)&x, (void*)&Wf, (void*)&bf, (void*)&Wg, (void*)&bg,
                  (void*)&Wh, (void*)&bh, (void*)&fh, (void*)&gh, (void*)&vT,
                  (void*)&out};
  hipLaunchCooperativeKernel((void*)fused_kernel, dim3(256), dim3(512), args, 0, stream);
}

// Round 4
// 90.640 us; speedup vs baseline: 2.1396x; 2.1396x over previous
//
#include <hip/hip_runtime.h>
#include <hip/hip_bf16.h>
#include <hip/hip_fp16.h>

typedef _Float16 half8_t  __attribute__((ext_vector_type(8)));
typedef short    short8_t __attribute__((ext_vector_type(8)));
typedef short    short4_t __attribute__((ext_vector_type(4)));
typedef float    f32x4    __attribute__((ext_vector_type(4)));

#define LOG2E 1.44269504088896f

__device__ __forceinline__ unsigned pack_bf16_2(float lo, float hi) {
  float2 f2; f2.x = lo; f2.y = hi;
  __hip_bfloat162 h2 = __float22bfloat162_rn(f2);
  return *reinterpret_cast<unsigned*>(&h2);
}

// ---------------------------------------------------------------------------
// Kernel 1 (v8): MFMA prep. One block = 64 positions; wave w = 16-pos m-tile.
// C = x[64 x 64] @ W[64 x 80] via 16x16x32 f16 MFMA (fp32 acc); W^T staged in
// LDS ([ch][c], stride 72 halves). Epilogue writes attn's exact layouts:
//   f  (ch 0-7):  key-permuted slots (slot = (j<4)? q8*4+j : 16+q8*4+j-4)
//   g  (ch 8-15): [pos][8], W/b pre-scaled by log2e
//   vT4(ch16-79): [b][kblock][ch][r] bf16
// ---------------------------------------------------------------------------
__global__ __launch_bounds__(256) void prep_kernel(
    const float* __restrict__ x,
    const float* __restrict__ Wf, const float* __restrict__ bf,
    const float* __restrict__ Wg, const float* __restrict__ bg,
    const float* __restrict__ Wh, const float* __restrict__ bh,
    _Float16* __restrict__ fh, _Float16* __restrict__ gh,
    unsigned short* __restrict__ vT)
{
  __shared__ _Float16 WtT[80 * 72];   // [ch][c], stride 72
  __shared__ float ball[80];
  const int t = threadIdx.x;

  for (int i = t; i < 512; i += 256) {
    int c = i >> 3, d = i & 7;
    WtT[d * 72 + c]       = (_Float16)Wf[i];
    WtT[(8 + d) * 72 + c] = (_Float16)(Wg[i] * LOG2E);
  }
  for (int i = t; i < 4096; i += 256) {
    int c = i >> 6, ch = i & 63;
    WtT[(16 + ch) * 72 + c] = (_Float16)Wh[i];
  }
  if (t < 80) ball[t] = (t < 8) ? bf[t] : (t < 16) ? bg[t - 8] * LOG2E : bh[t - 16];
  __syncthreads();

  const int lane = t & 63, w = t >> 6;
  const int quad = lane >> 4, l15 = lane & 15;
  const int p0 = blockIdx.x * 64;
  const int row = p0 + w * 16 + l15;

  const float* xr = x + (size_t)row * 64 + quad * 8;
  float4 xa = *(const float4*)(xr);
  float4 xb = *(const float4*)(xr + 4);
  float4 xc = *(const float4*)(xr + 32);
  float4 xd = *(const float4*)(xr + 36);
  half8_t a0, a1;
  a0[0]=(_Float16)xa.x; a0[1]=(_Float16)xa.y; a0[2]=(_Float16)xa.z; a0[3]=(_Float16)xa.w;
  a0[4]=(_Float16)xb.x; a0[5]=(_Float16)xb.y; a0[6]=(_Float16)xb.z; a0[7]=(_Float16)xb.w;
  a1[0]=(_Float16)xc.x; a1[1]=(_Float16)xc.y; a1[2]=(_Float16)xc.z; a1[3]=(_Float16)xc.w;
  a1[4]=(_Float16)xd.x; a1[5]=(_Float16)xd.y; a1[6]=(_Float16)xd.z; a1[7]=(_Float16)xd.w;

  const f32x4 zc = {0.f, 0.f, 0.f, 0.f};
  const int b     = p0 >> 12;
  const int nbase = (p0 & 4095) + w * 16 + quad * 4;
  const int kblock = nbase >> 5;
  const int r0     = nbase & 31;
  const int q8 = r0 >> 3, j8 = r0 & 7;
  const int slot0 = (j8 < 4) ? (q8 * 4 + j8) : (16 + q8 * 4 + (j8 - 4));
  const size_t fbase_out = ((size_t)b * 4096 + (kblock << 5) + slot0) * 8;
  const size_t gbase_out = ((size_t)p0 + w * 16 + quad * 4) * 8;
  const size_t vbase_out = (((size_t)b * 128 + kblock) << 11) + r0;

#pragma unroll
  for (int nt = 0; nt < 5; nt++) {
    const int ch0 = nt * 16 + l15;
    const _Float16* wt = &WtT[ch0 * 72 + quad * 8];
    half8_t b0 = *(const half8_t*)(wt);
    half8_t b1 = *(const half8_t*)(wt + 32);
    f32x4 d = __builtin_amdgcn_mfma_f32_16x16x32_f16(a0, b0, zc, 0, 0, 0);
    d = __builtin_amdgcn_mfma_f32_16x16x32_f16(a1, b1, d, 0, 0, 0);
    const float bias = ball[ch0];
    if (nt == 0) {
      if (l15 < 8) {
#pragma unroll
        for (int reg = 0; reg < 4; reg++)
          fh[fbase_out + (size_t)reg * 8 + l15] = (_Float16)(d[reg] + bias);
      } else {
#pragma unroll
        for (int reg = 0; reg < 4; reg++)
          gh[gbase_out + (size_t)reg * 8 + (l15 - 8)] = (_Float16)(d[reg] + bias);
      }
    } else {
      const int vch = ch0 - 16;
      union { unsigned u[2]; short4_t s; } pk;
      pk.u[0] = pack_bf16_2(d[0] + bias, d[1] + bias);
      pk.u[1] = pack_bf16_2(d[2] + bias, d[3] + bias);
      *(short4_t*)(vT + vbase_out + (size_t)vch * 32) = pk.s;
    }
  }
}

// ---------------------------------------------------------------------------
// Kernel 2 (v17): v15 structure (256 blocks x 512 thr, 64 queries/block,
// wave w = keys [w*512,+512), phase-staggered chunks, exp2-as-PV-B-frags,
// ones-MFMA denominator, ping-pong prefetch) + SCRATCH-SPILL FIX:
// the combine loop was `#pragma unroll 1` with acc[tt] runtime-indexed ->
// rule #20: the ENTIRE acc[4][4] lived in scratch all kernel (evidence:
// VGPR_Count 88 << ~150 live state; WRITE_SIZE 36.9 MB vs 4 MiB output =
// ~34 MB of spill traffic; all pipes idle on vmcnt). Fix: fully unroll the
// combine (all acc indices compile-time), accumulate partials IN PLACE into
// acc[tt], defer all out-stores past the last barrier (no vmcnt(0) drains
// inside the combine). Main loop unchanged (already statically indexed).
// ---------------------------------------------------------------------------
__device__ __forceinline__ void compute_chunk(
    const half8_t& f0, const half8_t& f1,
    const short8_t& v0, const short8_t& v1,
    const short8_t& v2, const short8_t& v3,
    const half8_t (&gfrag)[4], const short8_t& ones8,
    f32x4 (&acc)[4][4], f32x4 (&acc4)[4])
{
  const f32x4 zc = {0.f, 0.f, 0.f, 0.f};
#pragma unroll
  for (int tt = 0; tt < 4; tt++) {
    f32x4 s0 = __builtin_amdgcn_mfma_f32_16x16x32_f16(f0, gfrag[tt], zc, 0, 0, 0);
    f32x4 s1 = __builtin_amdgcn_mfma_f32_16x16x32_f16(f1, gfrag[tt], zc, 0, 0, 0);
    float p00 = __builtin_amdgcn_exp2f(s0[0]), p01 = __builtin_amdgcn_exp2f(s0[1]);
    float p02 = __builtin_amdgcn_exp2f(s0[2]), p03 = __builtin_amdgcn_exp2f(s0[3]);
    float p10 = __builtin_amdgcn_exp2f(s1[0]), p11 = __builtin_amdgcn_exp2f(s1[1]);
    float p12 = __builtin_amdgcn_exp2f(s1[2]), p13 = __builtin_amdgcn_exp2f(s1[3]);
    union { unsigned u[4]; short8_t v; } pu;
    pu.u[0] = pack_bf16_2(p00, p01);
    pu.u[1] = pack_bf16_2(p02, p03);
    pu.u[2] = pack_bf16_2(p10, p11);
    pu.u[3] = pack_bf16_2(p12, p13);
    short8_t pfrag = pu.v;
    acc[tt][0] = __builtin_amdgcn_mfma_f32_16x16x32_bf16(v0, pfrag, acc[tt][0], 0, 0, 0);
    acc[tt][1] = __builtin_amdgcn_mfma_f32_16x16x32_bf16(v1, pfrag, acc[tt][1], 0, 0, 0);
    acc[tt][2] = __builtin_amdgcn_mfma_f32_16x16x32_bf16(v2, pfrag, acc[tt][2], 0, 0, 0);
    acc[tt][3] = __builtin_amdgcn_mfma_f32_16x16x32_bf16(v3, pfrag, acc[tt][3], 0, 0, 0);
    acc4[tt]   = __builtin_amdgcn_mfma_f32_16x16x32_bf16(ones8, pfrag, acc4[tt], 0, 0, 0);
  }
}

__global__ __launch_bounds__(512, 2) void attn_kernel(
    const _Float16* __restrict__ fh,        // [B][N][8] f16, key-permuted slots
    const _Float16* __restrict__ gh,        // [B][N][8] f16 (x log2e)
    const unsigned short* __restrict__ vT,  // [b][kblock][ch][r] bf16
    float* __restrict__ out)                // [B][N][64] f32
{
  const int N    = 4096;
  const int lane = threadIdx.x & 63;
  const int w    = threadIdx.x >> 6;       // 0..7 = key range
  const int quad = lane >> 4;
  const int l15  = lane & 15;

  __shared__ float red[7][64][17];

  const int xcd = blockIdx.x & 7;
  const int b   = xcd >> 1;
  const int qg  = ((blockIdx.x >> 3) << 1) + (xcd & 1);  // 0..63
  const int q0  = qg * 64;
  const int kbase = w * 512;
  const int phase = (qg >> 1) & 15;        // stagger: de-correlate L2 streams

  const _Float16* fbase = fh + (size_t)b * N * 8;
  const _Float16* gbase = gh + (size_t)b * N * 8;
  const short*    vbat  = (const short*)vT + (size_t)b * 262144 + (l15 << 5) + (quad << 3);

  half8_t gfrag[4] = {{}, {}, {}, {}};
  if (quad == 0) {
#pragma unroll
    for (int tt = 0; tt < 4; tt++)
      gfrag[tt] = *(const half8_t*)(gbase + (size_t)(q0 + tt * 16 + l15) * 8);
  }

  const f32x4 zc = {0.f, 0.f, 0.f, 0.f};
  f32x4 acc[4][4];
  f32x4 acc4[4];
#pragma unroll
  for (int tt = 0; tt < 4; tt++) {
    acc4[tt] = zc;
#pragma unroll
    for (int ct = 0; ct < 4; ct++) acc[tt][ct] = zc;
  }

  short8_t ones8;
#pragma unroll
  for (int i = 0; i < 8; i++) ones8[i] = (short)0x3F80;

  // ping-pong load buffers
  half8_t  fa0 = {}, fa1 = {}, fb0 = {}, fb1 = {};
  short8_t va0, va1, va2, va3, vb0, vb1, vb2, vb3;

  {
    const int k0 = kbase + (((0 + phase) & 15) << 5);
    if (quad == 0) {
      fa0 = *(const half8_t*)(fbase + (size_t)(k0 + l15) * 8);
      fa1 = *(const half8_t*)(fbase + (size_t)(k0 + 16 + l15) * 8);
    }
    const short* vk = vbat + ((size_t)(k0 >> 5) << 11);
    va0 = *(const short8_t*)(vk);
    va1 = *(const short8_t*)(vk + 512);
    va2 = *(const short8_t*)(vk + 1024);
    va3 = *(const short8_t*)(vk + 1536);
  }

#pragma unroll 1
  for (int cc = 0; cc < 16; cc += 2) {
    {
      const int k1 = kbase + (((cc + 1 + phase) & 15) << 5);
      if (quad == 0) {
        fb0 = *(const half8_t*)(fbase + (size_t)(k1 + l15) * 8);
        fb1 = *(const half8_t*)(fbase + (size_t)(k1 + 16 + l15) * 8);
      }
      const short* vk = vbat + ((size_t)(k1 >> 5) << 11);
      vb0 = *(const short8_t*)(vk);
      vb1 = *(const short8_t*)(vk + 512);
      vb2 = *(const short8_t*)(vk + 1024);
      vb3 = *(const short8_t*)(vk + 1536);
    }
    compute_chunk(fa0, fa1, va0, va1, va2, va3, gfrag, ones8, acc, acc4);
    if (cc + 2 < 16) {
      const int k2 = kbase + (((cc + 2 + phase) & 15) << 5);
      if (quad == 0) {
        fa0 = *(const half8_t*)(fbase + (size_t)(k2 + l15) * 8);
        fa1 = *(const half8_t*)(fbase + (size_t)(k2 + 16 + l15) * 8);
      }
      const short* vk = vbat + ((size_t)(k2 >> 5) << 11);
      va0 = *(const short8_t*)(vk);
      va1 = *(const short8_t*)(vk + 512);
      va2 = *(const short8_t*)(vk + 1024);
      va3 = *(const short8_t*)(vk + 1536);
    }
    compute_chunk(fb0, fb1, vb0, vb1, vb2, vb3, gfrag, ones8, acc, acc4);
  }

  // ---- cross-wave combine: FULLY UNROLLED (static acc indices -> acc stays
  // in VGPRs), in-place accumulation, stores deferred past last barrier ----
#pragma unroll
  for (int tt = 0; tt < 4; tt++) {
    if (w > 0) {
      float* p = &red[w - 1][lane][0];
#pragma unroll
      for (int ct = 0; ct < 4; ct++)
#pragma unroll
        for (int reg = 0; reg < 4; reg++) p[ct * 4 + reg] = acc[tt][ct][reg];
      p[16] = acc4[tt][0];
    }
    __syncthreads();
    if (w == 0) {
#pragma unroll
      for (int ww = 0; ww < 7; ww++) {
        const float* p = &red[ww][lane][0];
#pragma unroll
        for (int reg = 0; reg < 4; reg++) {
          acc[tt][0][reg] += p[0 + reg];
          acc[tt][1][reg] += p[4 + reg];
          acc[tt][2][reg] += p[8 + reg];
          acc[tt][3][reg] += p[12 + reg];
        }
        acc4[tt][0] += p[16];
      }
    }
    if (tt < 3) __syncthreads();
  }

  if (w == 0) {
#pragma unroll
    for (int tt = 0; tt < 4; tt++) {
      const float inv = 1.0f / acc4[tt][0];
      float* ob = out + ((size_t)b * N + q0 + tt * 16 + l15) * 64 + (quad << 2);
      *(f32x4*)(ob)      = acc[tt][0] * inv;
      *(f32x4*)(ob + 16) = acc[tt][1] * inv;
      *(f32x4*)(ob + 32) = acc[tt][2] * inv;
      *(f32x4*)(ob + 48) = acc[tt][3] * inv;
    }
  }
}

// ---------------------------------------------------------------------------
extern "C" void kernel_launch(void* const* d_in, const int* in_sizes, int n_in,
                              void* d_out, int out_size, void* d_ws, size_t ws_size,
                              hipStream_t stream) {
  const float* x  = (const float*)d_in[0];
  const float* Wf = (const float*)d_in[1];
  const float* bf = (const float*)d_in[2];
  const float* Wg = (const float*)d_in[3];
  const float* bg = (const float*)d_in[4];
  const float* Wh = (const float*)d_in[5];
  const float* bh = (const float*)d_in[6];
  float* out = (float*)d_out;

  char* ws = (char*)d_ws;
  _Float16* fh = (_Float16*)ws;                        // 256 KB
  _Float16* gh = (_Float16*)(ws + 262144);             // 256 KB
  unsigned short* vT = (unsigned short*)(ws + 524288); // 2 MB

  prep_kernel<<<256, 256, 0, stream>>>(x, Wf, bf, Wg, bg, Wh, bh, fh, gh, vT);
  attn_kernel<<<256, 512, 0, stream>>>(fh, gh, vT, out);
}

// Round 5
// 89.178 us; speedup vs baseline: 2.1747x; 1.0164x over previous
//
#include <hip/hip_runtime.h>
#include <hip/hip_bf16.h>
#include <hip/hip_fp16.h>

typedef _Float16 half8_t  __attribute__((ext_vector_type(8)));
typedef short    short8_t __attribute__((ext_vector_type(8)));
typedef short    short4_t __attribute__((ext_vector_type(4)));
typedef float    f32x4    __attribute__((ext_vector_type(4)));

#define LOG2E 1.44269504088896f

__device__ __forceinline__ unsigned pack_bf16_2(float lo, float hi) {
  float2 f2; f2.x = lo; f2.y = hi;
  __hip_bfloat162 h2 = __float22bfloat162_rn(f2);
  return *reinterpret_cast<unsigned*>(&h2);
}

// ---------------------------------------------------------------------------
// Kernel 1 (v9): MFMA prep, 8-wave split (was 4 waves x 5 tiles).
// One block = 64 positions, 512 threads. Wave (wr, half): wr = wv&3 row-tile,
// half 0 -> nt 0..2, half 1 -> nt 3..4 (halves the per-wave MFMA critical
// path; logic identical to round-3 fused phase 1, which passed correctness).
// Outputs attn's exact layouts: f key-permuted slots, g (x log2e), vT bf16.
// ---------------------------------------------------------------------------
__global__ __launch_bounds__(512) void prep_kernel(
    const float* __restrict__ x,
    const float* __restrict__ Wf, const float* __restrict__ bf,
    const float* __restrict__ Wg, const float* __restrict__ bg,
    const float* __restrict__ Wh, const float* __restrict__ bh,
    _Float16* __restrict__ fh, _Float16* __restrict__ gh,
    unsigned short* __restrict__ vT)
{
  __shared__ _Float16 WtT[80 * 72];   // [ch][c], stride 72
  __shared__ float ball[80];
  const int t = threadIdx.x;

  {
    int c = t >> 3, d = t & 7;       // 512 threads cover Wf/Wg in one pass
    WtT[d * 72 + c]       = (_Float16)Wf[t];
    WtT[(8 + d) * 72 + c] = (_Float16)(Wg[t] * LOG2E);
  }
  for (int i = t; i < 4096; i += 512) {
    int c = i >> 6, ch = i & 63;
    WtT[(16 + ch) * 72 + c] = (_Float16)Wh[i];
  }
  if (t < 80) ball[t] = (t < 8) ? bf[t] : (t < 16) ? bg[t - 8] * LOG2E : bh[t - 16];
  __syncthreads();

  const int lane = t & 63, wv = t >> 6;
  const int quad = lane >> 4, l15 = lane & 15;
  const int wr   = wv & 3;       // row tile
  const int hsel = wv >> 2;      // 0: nt 0..2, 1: nt 3..4
  const int p0  = blockIdx.x * 64;
  const int row = p0 + wr * 16 + l15;

  const float* xr = x + (size_t)row * 64 + quad * 8;
  float4 xa = *(const float4*)(xr);
  float4 xb = *(const float4*)(xr + 4);
  float4 xc = *(const float4*)(xr + 32);
  float4 xd = *(const float4*)(xr + 36);
  half8_t a0, a1;
  a0[0]=(_Float16)xa.x; a0[1]=(_Float16)xa.y; a0[2]=(_Float16)xa.z; a0[3]=(_Float16)xa.w;
  a0[4]=(_Float16)xb.x; a0[5]=(_Float16)xb.y; a0[6]=(_Float16)xb.z; a0[7]=(_Float16)xb.w;
  a1[0]=(_Float16)xc.x; a1[1]=(_Float16)xc.y; a1[2]=(_Float16)xc.z; a1[3]=(_Float16)xc.w;
  a1[4]=(_Float16)xd.x; a1[5]=(_Float16)xd.y; a1[6]=(_Float16)xd.z; a1[7]=(_Float16)xd.w;

  const f32x4 zc = {0.f, 0.f, 0.f, 0.f};
  const int b     = p0 >> 12;
  const int nbase = (p0 & 4095) + wr * 16 + quad * 4;
  const int kblock = nbase >> 5;
  const int r0     = nbase & 31;
  const int q8 = r0 >> 3, j8 = r0 & 7;
  const int slot0 = (j8 < 4) ? (q8 * 4 + j8) : (16 + q8 * 4 + (j8 - 4));
  const size_t fbase_out = ((size_t)b * 4096 + (kblock << 5) + slot0) * 8;
  const size_t gbase_out = ((size_t)p0 + wr * 16 + quad * 4) * 8;
  const size_t vbase_out = (((size_t)b * 128 + kblock) << 11) + r0;

  if (hsel == 0) {
    // nt = 0: f (ch 0-7) / g (ch 8-15)
    {
      const _Float16* wt = &WtT[l15 * 72 + quad * 8];
      half8_t b0 = *(const half8_t*)(wt);
      half8_t b1 = *(const half8_t*)(wt + 32);
      f32x4 d = __builtin_amdgcn_mfma_f32_16x16x32_f16(a0, b0, zc, 0, 0, 0);
      d = __builtin_amdgcn_mfma_f32_16x16x32_f16(a1, b1, d, 0, 0, 0);
      const float bias = ball[l15];
      if (l15 < 8) {
#pragma unroll
        for (int reg = 0; reg < 4; reg++)
          fh[fbase_out + (size_t)reg * 8 + l15] = (_Float16)(d[reg] + bias);
      } else {
#pragma unroll
        for (int reg = 0; reg < 4; reg++)
          gh[gbase_out + (size_t)reg * 8 + (l15 - 8)] = (_Float16)(d[reg] + bias);
      }
    }
#pragma unroll
    for (int nt = 1; nt < 3; nt++) {
      const int ch0 = nt * 16 + l15;
      const _Float16* wt = &WtT[ch0 * 72 + quad * 8];
      half8_t b0 = *(const half8_t*)(wt);
      half8_t b1 = *(const half8_t*)(wt + 32);
      f32x4 d = __builtin_amdgcn_mfma_f32_16x16x32_f16(a0, b0, zc, 0, 0, 0);
      d = __builtin_amdgcn_mfma_f32_16x16x32_f16(a1, b1, d, 0, 0, 0);
      const float bias = ball[ch0];
      const int vch = ch0 - 16;
      union { unsigned u[2]; short4_t s; } pk;
      pk.u[0] = pack_bf16_2(d[0] + bias, d[1] + bias);
      pk.u[1] = pack_bf16_2(d[2] + bias, d[3] + bias);
      *(short4_t*)(vT + vbase_out + (size_t)vch * 32) = pk.s;
    }
  } else {
#pragma unroll
    for (int nt = 3; nt < 5; nt++) {
      const int ch0 = nt * 16 + l15;
      const _Float16* wt = &WtT[ch0 * 72 + quad * 8];
      half8_t b0 = *(const half8_t*)(wt);
      half8_t b1 = *(const half8_t*)(wt + 32);
      f32x4 d = __builtin_amdgcn_mfma_f32_16x16x32_f16(a0, b0, zc, 0, 0, 0);
      d = __builtin_amdgcn_mfma_f32_16x16x32_f16(a1, b1, d, 0, 0, 0);
      const float bias = ball[ch0];
      const int vch = ch0 - 16;
      union { unsigned u[2]; short4_t s; } pk;
      pk.u[0] = pack_bf16_2(d[0] + bias, d[1] + bias);
      pk.u[1] = pack_bf16_2(d[2] + bias, d[3] + bias);
      *(short4_t*)(vT + vbase_out + (size_t)vch * 32) = pk.s;
    }
  }
}

// ---------------------------------------------------------------------------
// Kernel 2 (v18): v17 (spill-fixed combine) + DEEP PREFETCH.
// Old ping-pong issued chunk cc+1's loads right before computing cc
// (distance ~1 compute_chunk ~= 180 cy < L2 latency ~200+ cy under
// contention). Now 4 live chunk-buffers, 4 chunks/iteration: every load
// lands >= 2 compute_chunks (~400 cy) before its use. VGPR est ~205
// (cap 256 at (512,2)); regression signature would be attn back in top-5
// with WRITE_SIZE >> 4 MiB (spill).
// ---------------------------------------------------------------------------
__device__ __forceinline__ void compute_chunk(
    const half8_t& f0, const half8_t& f1,
    const short8_t& v0, const short8_t& v1,
    const short8_t& v2, const short8_t& v3,
    const half8_t (&gfrag)[4], const short8_t& ones8,
    f32x4 (&acc)[4][4], f32x4 (&acc4)[4])
{
  const f32x4 zc = {0.f, 0.f, 0.f, 0.f};
#pragma unroll
  for (int tt = 0; tt < 4; tt++) {
    f32x4 s0 = __builtin_amdgcn_mfma_f32_16x16x32_f16(f0, gfrag[tt], zc, 0, 0, 0);
    f32x4 s1 = __builtin_amdgcn_mfma_f32_16x16x32_f16(f1, gfrag[tt], zc, 0, 0, 0);
    float p00 = __builtin_amdgcn_exp2f(s0[0]), p01 = __builtin_amdgcn_exp2f(s0[1]);
    float p02 = __builtin_amdgcn_exp2f(s0[2]), p03 = __builtin_amdgcn_exp2f(s0[3]);
    float p10 = __builtin_amdgcn_exp2f(s1[0]), p11 = __builtin_amdgcn_exp2f(s1[1]);
    float p12 = __builtin_amdgcn_exp2f(s1[2]), p13 = __builtin_amdgcn_exp2f(s1[3]);
    union { unsigned u[4]; short8_t v; } pu;
    pu.u[0] = pack_bf16_2(p00, p01);
    pu.u[1] = pack_bf16_2(p02, p03);
    pu.u[2] = pack_bf16_2(p10, p11);
    pu.u[3] = pack_bf16_2(p12, p13);
    short8_t pfrag = pu.v;
    acc[tt][0] = __builtin_amdgcn_mfma_f32_16x16x32_bf16(v0, pfrag, acc[tt][0], 0, 0, 0);
    acc[tt][1] = __builtin_amdgcn_mfma_f32_16x16x32_bf16(v1, pfrag, acc[tt][1], 0, 0, 0);
    acc[tt][2] = __builtin_amdgcn_mfma_f32_16x16x32_bf16(v2, pfrag, acc[tt][2], 0, 0, 0);
    acc[tt][3] = __builtin_amdgcn_mfma_f32_16x16x32_bf16(v3, pfrag, acc[tt][3], 0, 0, 0);
    acc4[tt]   = __builtin_amdgcn_mfma_f32_16x16x32_bf16(ones8, pfrag, acc4[tt], 0, 0, 0);
  }
}

__global__ __launch_bounds__(512, 2) void attn_kernel(
    const _Float16* __restrict__ fh,        // [B][N][8] f16, key-permuted slots
    const _Float16* __restrict__ gh,        // [B][N][8] f16 (x log2e)
    const unsigned short* __restrict__ vT,  // [b][kblock][ch][r] bf16
    float* __restrict__ out)                // [B][N][64] f32
{
  const int N    = 4096;
  const int lane = threadIdx.x & 63;
  const int w    = threadIdx.x >> 6;       // 0..7 = key range
  const int quad = lane >> 4;
  const int l15  = lane & 15;

  __shared__ float red[7][64][17];

  const int xcd = blockIdx.x & 7;
  const int b   = xcd >> 1;
  const int qg  = ((blockIdx.x >> 3) << 1) + (xcd & 1);  // 0..63
  const int q0  = qg * 64;
  const int kbase = w * 512;
  const int phase = (qg >> 1) & 15;        // stagger: de-correlate L2 streams

  const _Float16* fbase = fh + (size_t)b * N * 8;
  const _Float16* gbase = gh + (size_t)b * N * 8;
  const short*    vbat  = (const short*)vT + (size_t)b * 262144 + (l15 << 5) + (quad << 3);

  half8_t gfrag[4] = {{}, {}, {}, {}};
  if (quad == 0) {
#pragma unroll
    for (int tt = 0; tt < 4; tt++)
      gfrag[tt] = *(const half8_t*)(gbase + (size_t)(q0 + tt * 16 + l15) * 8);
  }

  const f32x4 zc = {0.f, 0.f, 0.f, 0.f};
  f32x4 acc[4][4];
  f32x4 acc4[4];
#pragma unroll
  for (int tt = 0; tt < 4; tt++) {
    acc4[tt] = zc;
#pragma unroll
    for (int ct = 0; ct < 4; ct++) acc[tt][ct] = zc;
  }

  short8_t ones8;
#pragma unroll
  for (int i = 0; i < 8; i++) ones8[i] = (short)0x3F80;

#define KOFF(j) (kbase + ((((j) + phase) & 15) << 5))
#define LOADC(k, F0, F1, V0, V1, V2, V3)                                  \
  {                                                                       \
    const int kk = (k);                                                   \
    if (quad == 0) {                                                      \
      F0 = *(const half8_t*)(fbase + (size_t)(kk + l15) * 8);             \
      F1 = *(const half8_t*)(fbase + (size_t)(kk + 16 + l15) * 8);        \
    }                                                                     \
    const short* vk = vbat + ((size_t)(kk >> 5) << 11);                   \
    V0 = *(const short8_t*)(vk);                                          \
    V1 = *(const short8_t*)(vk + 512);                                    \
    V2 = *(const short8_t*)(vk + 1024);                                   \
    V3 = *(const short8_t*)(vk + 1536);                                   \
  }

  // 4 chunk-buffers A,B,C,D
  half8_t  fA0 = {}, fA1 = {}, fB0 = {}, fB1 = {};
  half8_t  fC0 = {}, fC1 = {}, fD0 = {}, fD1 = {};
  short8_t vA0, vA1, vA2, vA3, vB0, vB1, vB2, vB3;
  short8_t vC0, vC1, vC2, vC3, vD0, vD1, vD2, vD3;

  LOADC(KOFF(0), fA0, fA1, vA0, vA1, vA2, vA3);
  LOADC(KOFF(1), fB0, fB1, vB0, vB1, vB2, vB3);

#pragma unroll 1
  for (int cc = 0; cc < 16; cc += 4) {
    LOADC(KOFF(cc + 2), fC0, fC1, vC0, vC1, vC2, vC3);
    LOADC(KOFF(cc + 3), fD0, fD1, vD0, vD1, vD2, vD3);
    compute_chunk(fA0, fA1, vA0, vA1, vA2, vA3, gfrag, ones8, acc, acc4);
    compute_chunk(fB0, fB1, vB0, vB1, vB2, vB3, gfrag, ones8, acc, acc4);
    if (cc + 4 < 16) {
      LOADC(KOFF(cc + 4), fA0, fA1, vA0, vA1, vA2, vA3);
      LOADC(KOFF(cc + 5), fB0, fB1, vB0, vB1, vB2, vB3);
    }
    compute_chunk(fC0, fC1, vC0, vC1, vC2, vC3, gfrag, ones8, acc, acc4);
    compute_chunk(fD0, fD1, vD0, vD1, vD2, vD3, gfrag, ones8, acc, acc4);
  }
#undef LOADC
#undef KOFF

  // ---- cross-wave combine: fully unrolled (static acc indices), in-place
  // accumulation, stores deferred past last barrier ----
#pragma unroll
  for (int tt = 0; tt < 4; tt++) {
    if (w > 0) {
      float* p = &red[w - 1][lane][0];
#pragma unroll
      for (int ct = 0; ct < 4; ct++)
#pragma unroll
        for (int reg = 0; reg < 4; reg++) p[ct * 4 + reg] = acc[tt][ct][reg];
      p[16] = acc4[tt][0];
    }
    __syncthreads();
    if (w == 0) {
#pragma unroll
      for (int ww = 0; ww < 7; ww++) {
        const float* p = &red[ww][lane][0];
#pragma unroll
        for (int reg = 0; reg < 4; reg++) {
          acc[tt][0][reg] += p[0 + reg];
          acc[tt][1][reg] += p[4 + reg];
          acc[tt][2][reg] += p[8 + reg];
          acc[tt][3][reg] += p[12 + reg];
        }
        acc4[tt][0] += p[16];
      }
    }
    if (tt < 3) __syncthreads();
  }

  if (w == 0) {
#pragma unroll
    for (int tt = 0; tt < 4; tt++) {
      const float inv = 1.0f / acc4[tt][0];
      float* ob = out + ((size_t)b * N + q0 + tt * 16 + l15) * 64 + (quad << 2);
      *(f32x4*)(ob)      = acc[tt][0] * inv;
      *(f32x4*)(ob + 16) = acc[tt][1] * inv;
      *(f32x4*)(ob + 32) = acc[tt][2] * inv;
      *(f32x4*)(ob + 48) = acc[tt][3] * inv;
    }
  }
}

// ---------------------------------------------------------------------------
extern "C" void kernel_launch(void* const* d_in, const int* in_sizes, int n_in,
                              void* d_out, int out_size, void* d_ws, size_t ws_size,
                              hipStream_t stream) {
  const float* x  = (const float*)d_in[0];
  const float* Wf = (const float*)d_in[1];
  const float* bf = (const float*)d_in[2];
  const float* Wg = (const float*)d_in[3];
  const float* bg = (const float*)d_in[4];
  const float* Wh = (const float*)d_in[5];
  const float* bh = (const float*)d_in[6];
  float* out = (float*)d_out;

  char* ws = (char*)d_ws;
  _Float16* fh = (_Float16*)ws;                        // 256 KB
  _Float16* gh = (_Float16*)(ws + 262144);             // 256 KB
  unsigned short* vT = (unsigned short*)(ws + 524288); // 2 MB

  prep_kernel<<<256, 512, 0, stream>>>(x, Wf, bf, Wg, bg, Wh, bh, fh, gh, vT);
  attn_kernel<<<256, 512, 0, stream>>>(fh, gh, vT, out);
}